// Round 6
// baseline (428.401 us; speedup 1.0000x reference)
//
#include <hip/hip_runtime.h>
#include <hip/hip_fp16.h>
#include <cmath>

// ---------------------------------------------------------------------------
// PlainGNN: Q/K/V = x@W^T ; per-edge scores = leakyrelu(scale * sum_d D*(K_i-Q_j)^2)
// (self edges: K^T diag(D) Q) ; segment-softmax over destination row ;
// out[row] += alpha * V[col].
// N=100000, E=1600000, IN_F=128, HEADS=4, D_K=32.
//
// R8: qkv on matrix cores (fp16 Markidis split) -> 566us. R9: fp16 QV gather
// -> 458us. R10: single-x-stage -> 445us. R11: bucket CSR + combined kernel
// -> 368us. R12: interleaved block types HURT (225us, occ 14%): LDS is
// allocated uniformly per block, so fill blocks wasted 64KB and interleave
// could not raise waves/CU — combined-kernel overlap is structurally broken.
// R13: (a) fill is its own kernel with ZERO LDS (32 waves/CU for the
// latency-bound scatter); (b) one-time split_w pre-splits W into fp16 hi/lo
// in EXACT MFMA fragment order, so qkv B-frags are single coalesced 16B/lane
// global loads (192KB, L2-resident) — deletes ws LDS (64->32KB, 4 blocks/CU),
// all per-block W restages, and 8 of 9 syncthreads; 24 MFMA per kc.
// ---------------------------------------------------------------------------

#define HEADS 4
#define DK 32
#define FDIM 128

typedef _Float16 f16x8 __attribute__((ext_vector_type(8)));
typedef float f32x4 __attribute__((ext_vector_type(4)));

// cursor=0 over N.
__global__ __launch_bounds__(256) void init_buffers(
    int* __restrict__ cursor, int n)
{
    int gid = blockIdx.x * 256 + threadIdx.x;
    if (gid < n) cursor[gid] = 0;
}

// One-time W split: Wq/Wk/Wv fp32 [128][128] -> fp16 hi/lo in fragment order.
// Layout: Whf/Wlf[((p*8 + g)*4 + kc)*64 + lane] * f16x8, where lane l holds
// W[g*16 + (l&15)][kc*32 + (l>>4)*8 .. +7]. One block per projection.
__global__ __launch_bounds__(256) void split_w(
    const float* __restrict__ Wq, const float* __restrict__ Wk,
    const float* __restrict__ Wv, _Float16* __restrict__ Whf,
    _Float16* __restrict__ Wlf)
{
    const int p = blockIdx.x;
    const float* __restrict__ W = (p == 0) ? Wq : (p == 1 ? Wk : Wv);
#pragma unroll
    for (int i = 0; i < 8; ++i) {
        const int id = i * 256 + threadIdx.x;     // 0..2047
        const int g  = id >> 8;
        const int kc = (id >> 6) & 3;
        const int l  = id & 63;
        const int row  = g * 16 + (l & 15);
        const int col0 = kc * 32 + (l >> 4) * 8;
        const float* src = W + row * FDIM + col0;
        const float4 v0 = *reinterpret_cast<const float4*>(src);
        const float4 v1 = *reinterpret_cast<const float4*>(src + 4);
        const float vv[8] = {v0.x, v0.y, v0.z, v0.w, v1.x, v1.y, v1.z, v1.w};
        f16x8 h, lo;
#pragma unroll
        for (int j = 0; j < 8; ++j) {
            _Float16 hh = (_Float16)vv[j];
            h[j]  = hh;
            lo[j] = (_Float16)(vv[j] - (float)hh);
        }
        const size_t off = ((size_t)((p * 8 + g) * 4 + kc) * 64 + l) * 8;
        *reinterpret_cast<f16x8*>(Whf + off) = h;
        *reinterpret_cast<f16x8*>(Wlf + off) = lo;
    }
}

// Standalone bucket fill: ZERO LDS -> full occupancy for the atomic/scatter
// stream. 4 edges/thread, int4 loads. 64-slot buckets (Poisson(16):
// P(deg>=64) ~ 1e-13; overflow edges dropped, fused clamps cnt).
__global__ __launch_bounds__(256) void fill_buckets(
    const int* __restrict__ row, const int* __restrict__ col,
    int* __restrict__ cursor, int* __restrict__ csr, int E, int N)
{
    const int t  = blockIdx.x * 256 + threadIdx.x;
    const int e0 = t * 4;
    if (e0 + 3 < E) {
        const int4 r4 = *reinterpret_cast<const int4*>(row + e0);
        const int4 c4 = *reinterpret_cast<const int4*>(col + e0);
        const int rr[4] = {r4.x, r4.y, r4.z, r4.w};
        const int cc[4] = {c4.x, c4.y, c4.z, c4.w};
#pragma unroll
        for (int k = 0; k < 4; ++k) {
            const int r = rr[k];
            if ((unsigned)r < (unsigned)N) {
                const int p = atomicAdd(&cursor[r], 1);
                if (p < 64) csr[(r << 6) + p] = cc[k];
            }
        }
    } else {
        for (int e = e0; e < E; ++e) {
            const int r = row[e];
            if ((unsigned)r < (unsigned)N) {
                const int p = atomicAdd(&cursor[r], 1);
                if (p < 64) csr[(r << 6) + p] = col[e];
            }
        }
    }
}

// Swizzled half-index for the x LDS tiles: logical [row][kk], row stride 128
// halves (256B). half-index ^= (row&7)<<3 spreads 256B-stride fragment reads
// across banks; 16B granules stay aligned.
__device__ __forceinline__ int swz_idx(int row, int kk) {
    return (row * FDIM + kk) ^ ((row & 7) << 3);
}

// Stage a 64x128 fp32 x tile ONCE, writing both hi and lo fp16 parts.
__device__ __forceinline__ void stage_x(
    const float* __restrict__ src, _Float16* __restrict__ dh,
    _Float16* __restrict__ dl, int n0, int nmax, int tid)
{
    const int kk0 = (tid & 15) * 8;
    const int r0  = tid >> 4;
#pragma unroll
    for (int i = 0; i < 4; ++i) {
        const int row = i * 16 + r0;
        float4 v0 = make_float4(0.f, 0.f, 0.f, 0.f), v1 = v0;
        if (n0 + row < nmax) {
            const float* p = src + (size_t)(n0 + row) * FDIM + kk0;
            v0 = *reinterpret_cast<const float4*>(p);
            v1 = *reinterpret_cast<const float4*>(p + 4);
        }
        const float vv[8] = {v0.x, v0.y, v0.z, v0.w, v1.x, v1.y, v1.z, v1.w};
        f16x8 h, l;
#pragma unroll
        for (int j = 0; j < 8; ++j) {
            _Float16 hh = (_Float16)vv[j];
            h[j] = hh;
            l[j] = (_Float16)(vv[j] - (float)hh);
        }
        const int si = swz_idx(row, kk0);
        *reinterpret_cast<f16x8*>(&dh[si]) = h;
        *reinterpret_cast<f16x8*>(&dl[si]) = l;
    }
}

// QKV projection on matrix cores, W-fragments streamed from pre-split global
// (coalesced 16B/lane, L2-resident). Block = 64-node tile, all 3 projections.
// Wave quadrant: wr0 = (wv>>1)*32, wc0 = (wv&1)*64; 2x4 frags, 24 MFMA/kc
// (afh*bfh + afl*bfh + afh*bfl). Q,V -> interleaved fp16 QVh[n][256] =
// [q0,q1,v0,v1]x64; K -> fp32 Kout (= d_out, aliased; see fused_aggregate).
__global__ __launch_bounds__(256) void qkv_gemm(
    const float* __restrict__ x, const _Float16* __restrict__ Whf,
    const _Float16* __restrict__ Wlf, __half* __restrict__ QVh,
    float* __restrict__ Kout, int N)
{
    __shared__ __align__(16) _Float16 xh[64 * 128];    // 16 KB
    __shared__ __align__(16) _Float16 xl[64 * 128];    // 16 KB

    const int n0  = blockIdx.x * 64;
    const int tid = threadIdx.x;
    const int lane = tid & 63;
    const int wv   = tid >> 6;
    const int wr0  = (wv >> 1) * 32;
    const int wc0  = (wv & 1) * 64;
    const int g0   = wc0 >> 4;          // base row-group for B frags
    const int orow = (lane >> 4) * 4;
    const int ocol = lane & 15;

    stage_x(x, xh, xl, n0, N, tid);
    __syncthreads();

    const int lrow = lane & 15;
    const int lk   = (lane >> 4) * 8;

    for (int p = 0; p < 3; ++p) {
        f32x4 acc[2][4];
#pragma unroll
        for (int a = 0; a < 2; ++a)
#pragma unroll
            for (int b = 0; b < 4; ++b)
                acc[a][b] = (f32x4){0.f, 0.f, 0.f, 0.f};

#pragma unroll
        for (int kc = 0; kc < 4; ++kc) {
            f16x8 afh[2], afl[2], bfh[4], bfl[4];
#pragma unroll
            for (int a = 0; a < 2; ++a) {
                const int si = swz_idx(wr0 + a * 16 + lrow, kc * 32 + lk);
                afh[a] = *reinterpret_cast<const f16x8*>(&xh[si]);
                afl[a] = *reinterpret_cast<const f16x8*>(&xl[si]);
            }
#pragma unroll
            for (int b = 0; b < 4; ++b) {
                const size_t off =
                    ((size_t)((p * 8 + g0 + b) * 4 + kc) * 64 + lane) * 8;
                bfh[b] = *reinterpret_cast<const f16x8*>(Whf + off);
                bfl[b] = *reinterpret_cast<const f16x8*>(Wlf + off);
            }
#pragma unroll
            for (int a = 0; a < 2; ++a)
#pragma unroll
                for (int b = 0; b < 4; ++b)
                    acc[a][b] = __builtin_amdgcn_mfma_f32_16x16x32_f16(
                        afh[a], bfh[b], acc[a][b], 0, 0, 0);
#pragma unroll
            for (int a = 0; a < 2; ++a)
#pragma unroll
                for (int b = 0; b < 4; ++b)
                    acc[a][b] = __builtin_amdgcn_mfma_f32_16x16x32_f16(
                        afl[a], bfh[b], acc[a][b], 0, 0, 0);
#pragma unroll
            for (int a = 0; a < 2; ++a)
#pragma unroll
                for (int b = 0; b < 4; ++b)
                    acc[a][b] = __builtin_amdgcn_mfma_f32_16x16x32_f16(
                        afh[a], bfl[b], acc[a][b], 0, 0, 0);
        }

        // epilogue for projection p
        if (p == 1) {
#pragma unroll
            for (int a = 0; a < 2; ++a) {
#pragma unroll
                for (int r = 0; r < 4; ++r) {
                    const int n = n0 + wr0 + a * 16 + orow + r;
                    if (n < N) {
                        float* op = Kout + (size_t)n * FDIM + wc0 + ocol;
#pragma unroll
                        for (int b = 0; b < 4; ++b)
                            op[b * 16] = acc[a][b][r];
                    }
                }
            }
        } else {
            const int voff = (p == 2) ? 2 : 0;
#pragma unroll
            for (int a = 0; a < 2; ++a) {
#pragma unroll
                for (int r = 0; r < 4; ++r) {
                    const int n = n0 + wr0 + a * 16 + orow + r;
                    if (n < N) {
                        __half* op = QVh + (size_t)n * 256;
#pragma unroll
                        for (int b = 0; b < 4; ++b) {
                            const int d_o = wc0 + ocol + b * 16;
                            op[((d_o >> 1) << 2) + (d_o & 1) + voff] =
                                __float2half(acc[a][b][r]);
                        }
                    }
                }
            }
        }
    }
}

// Fused scores+softmax+aggregate. One wave per dst node; lane holds dims
// (2*lane, 2*lane+1), head = lane>>4 (16-lane groups). K[node] fp32 from
// Kb (= out, aliased: each wave reads only its own row before writing it).
// Neighbor ids: cnt<=64, one coalesced load + __shfl broadcast. Gathers:
// one 8B interleaved [q0,q1,v0,v1] load per lane per edge; 4-deep pipeline.
__global__ __launch_bounds__(256) void fused_aggregate(
    const int* __restrict__ cursor, const int* __restrict__ csr,
    const __half* __restrict__ QVh, const float* Kb,
    const float* __restrict__ D, float* out, int N)
{
    int node = blockIdx.x * 4 + (threadIdx.x >> 6);
    if (node >= N) return;
    int lane = threadIdx.x & 63;
    int d = lane * 2;
    const float2 kv = *reinterpret_cast<const float2*>(Kb + (size_t)node * FDIM + d);
    const float D0 = D[d], D1 = D[d + 1];
    int cnt = cursor[node];
    cnt = (cnt < 64) ? cnt : 64;
    const int j0 = node << 6;
    float a0 = 0.0f, a1 = 0.0f, se = 0.0f;

    int cc0, cc1, cc2, cc3;
    float2 t0, t1, t2, t3;

    const int ec = (lane < cnt) ? csr[j0 + lane] : 0;

#define LOADF(s, idx) { int c_ = __shfl(ec, (idx)); cc##s = c_; \
    t##s = *reinterpret_cast<const float2*>( \
        reinterpret_cast<const __half*>(QVh) + (size_t)c_ * 256 + (lane << 2)); }

#define PROC(s) { \
    float2 qf = __half22float2(*reinterpret_cast<__half2*>(&t##s.x)); \
    float2 vf = __half22float2(*reinterpret_cast<__half2*>(&t##s.y)); \
    float p; \
    if (cc##s == node) { p = D0 * kv.x * qf.x + D1 * kv.y * qf.y; } \
    else { float dx = kv.x - qf.x, dy = kv.y - qf.y; \
           p = D0 * dx * dx + D1 * dy * dy; } \
    p += __shfl_xor(p, 1); p += __shfl_xor(p, 2); \
    p += __shfl_xor(p, 4); p += __shfl_xor(p, 8); \
    float z = p * 0.17677669529663687f; \
    z = fmaxf(z, 0.2f * z); \
    float ex = __expf(z); \
    a0 += ex * vf.x; a1 += ex * vf.y; se += ex; }

    int j = 0;
    if (cnt >= 4) {
        LOADF(0, 0) LOADF(1, 1) LOADF(2, 2) LOADF(3, 3)
        while (j + 8 <= cnt) {
            PROC(0) LOADF(0, j + 4)
            PROC(1) LOADF(1, j + 5)
            PROC(2) LOADF(2, j + 6)
            PROC(3) LOADF(3, j + 7)
            j += 4;
        }
        PROC(0) PROC(1) PROC(2) PROC(3)
        j += 4;
    }
    for (; j < cnt; ++j) {
        LOADF(0, j)
        PROC(0)
    }
#undef LOADF
#undef PROC

    float inv = 1.0f / (se + 1e-16f);
    *reinterpret_cast<float2*>(out + (size_t)node * FDIM + d) =
        make_float2(a0 * inv, a1 * inv);
}

extern "C" void kernel_launch(void* const* d_in, const int* in_sizes, int n_in,
                              void* d_out, int out_size, void* d_ws, size_t ws_size,
                              hipStream_t stream) {
    const float* x  = (const float*)d_in[0];
    const float* Wq = (const float*)d_in[1];
    const float* Wk = (const float*)d_in[2];
    const float* Wv = (const float*)d_in[3];
    const float* D  = (const float*)d_in[4];
    const int*  edge = (const int*)d_in[5];
    float* out = (float*)d_out;

    const int N = in_sizes[0] / FDIM;
    const int E = in_sizes[5] / 2;
    const int* row = edge;       // edge_index[0] = destination (segment id)
    const int* col = edge + E;   // edge_index[1] = source of Q_j / V

    // Workspace: QVh[N][256] fp16 | cursor[N] | csr[N*64] | Whf | Wlf
    // K buffer lives in d_out (aliased; overwritten by fused_aggregate).
    __half* QVh = (__half*)d_ws;
    int* cursor = (int*)(QVh + (size_t)N * 256);
    int* csr    = cursor + N;                       // N*64 entries
    _Float16* Whf = (_Float16*)(csr + (size_t)N * 64);   // 3*16384 halves
    _Float16* Wlf = Whf + 3 * 16384;
    float* Kout = out;

    init_buffers<<<(N + 255) / 256, 256, 0, stream>>>(cursor, N);
    split_w<<<3, 256, 0, stream>>>(Wq, Wk, Wv, Whf, Wlf);

    fill_buckets<<<(E + 1023) / 1024, 256, 0, stream>>>(
        row, col, cursor, csr, E, N);

    qkv_gemm<<<(N + 63) / 64, 256, 0, stream>>>(
        x, Whf, Wlf, QVh, Kout, N);

    fused_aggregate<<<(N + 3) / 4, 256, 0, stream>>>(
        cursor, csr, QVh, Kout, D, out, N);
}

// Round 8
// 314.485 us; speedup vs baseline: 1.3622x; 1.3622x over previous
//
#include <hip/hip_runtime.h>
#include <hip/hip_fp16.h>
#include <cmath>

// ---------------------------------------------------------------------------
// PlainGNN: Q/K/V = x@W^T ; per-edge scores = leakyrelu(scale * sum_d D*(K_i-Q_j)^2)
// (self edges: K^T diag(D) Q) ; segment-softmax over destination row ;
// out[row] += alpha * V[col].
// N=100000, E=1600000, IN_F=128, HEADS=4, D_K=32.
//
// R11: bucket CSR + combined kernel -> 368us. R12: interleaved block types
// HURT (LDS uniform per block). R13: split kernels + zero-LDS fill -> 428us;
// fill_buckets 150us with WRITE_SIZE=96MB = ONE 64B writeback PER EDGE:
// sparse 64-slot buckets + cross-XCD L2 non-coherence means no write
// merging; 96MB random 64B writebacks at 0.64TB/s IS the 150us.
// R14: two-phase counting sort -> dense CSR. Phase A: LDS histogram over
// 256-node bins, ONE global atomic per (block,bin) (153k vs 1.6M), scatter
// packed 4B records (r&255 | col<<8) into fixed-cap bin regions (payload
// 6.4MB). Phase B: per-bin block: LDS deg count -> scan -> dense scatter
// (single-XCD, packed => writeback ~= payload). fused uses off/cnt + chunk
// loop. R15: R14 bench was an infra failure (container died twice, no
// counters); kernel re-audited (no OOB/hang candidates) and resubmitted
// unchanged to get the measurement.
// ---------------------------------------------------------------------------

#define HEADS 4
#define DK 32
#define FDIM 128
#define BINSHIFT 8
#define BINCAP 6144          // per-bin edge capacity; mean 4096, sd 64

typedef _Float16 f16x8 __attribute__((ext_vector_type(8)));
typedef float f32x4 __attribute__((ext_vector_type(4)));

// bin_cursor = 0 over NB bins.
__global__ __launch_bounds__(256) void init_buffers(
    int* __restrict__ bin_cursor, int nb)
{
    int gid = blockIdx.x * 256 + threadIdx.x;
    if (gid < nb) bin_cursor[gid] = 0;
}

// One-time W split: Wq/Wk/Wv fp32 [128][128] -> fp16 hi/lo in fragment order.
// Layout: Whf/Wlf[((p*8 + g)*4 + kc)*64 + lane] * f16x8, where lane l holds
// W[g*16 + (l&15)][kc*32 + (l>>4)*8 .. +7]. One block per projection.
__global__ __launch_bounds__(256) void split_w(
    const float* __restrict__ Wq, const float* __restrict__ Wk,
    const float* __restrict__ Wv, _Float16* __restrict__ Whf,
    _Float16* __restrict__ Wlf)
{
    const int p = blockIdx.x;
    const float* __restrict__ W = (p == 0) ? Wq : (p == 1 ? Wk : Wv);
#pragma unroll
    for (int i = 0; i < 8; ++i) {
        const int id = i * 256 + threadIdx.x;     // 0..2047
        const int g  = id >> 8;
        const int kc = (id >> 6) & 3;
        const int l  = id & 63;
        const int row  = g * 16 + (l & 15);
        const int col0 = kc * 32 + (l >> 4) * 8;
        const float* src = W + row * FDIM + col0;
        const float4 v0 = *reinterpret_cast<const float4*>(src);
        const float4 v1 = *reinterpret_cast<const float4*>(src + 4);
        const float vv[8] = {v0.x, v0.y, v0.z, v0.w, v1.x, v1.y, v1.z, v1.w};
        f16x8 h, lo;
#pragma unroll
        for (int j = 0; j < 8; ++j) {
            _Float16 hh = (_Float16)vv[j];
            h[j]  = hh;
            lo[j] = (_Float16)(vv[j] - (float)hh);
        }
        const size_t off = ((size_t)((p * 8 + g) * 4 + kc) * 64 + l) * 8;
        *reinterpret_cast<f16x8*>(Whf + off) = h;
        *reinterpret_cast<f16x8*>(Wlf + off) = lo;
    }
}

// Phase A: partition edges into 256-node bins. 4096 edges/block.
// LDS histogram -> one global atomicAdd per (block,bin) reserving a chunk ->
// scatter packed records (r&255)|(col<<8) into pairs[bin*BINCAP + pos].
__global__ __launch_bounds__(256) void partition_edges(
    const int* __restrict__ row, const int* __restrict__ col,
    int* __restrict__ bin_cursor, unsigned* __restrict__ pairs,
    int E, int N, int NB)
{
    __shared__ int hist[512];
    __shared__ int basea[512];
    __shared__ int cura[512];
    const int tid = threadIdx.x;
    for (int b = tid; b < 512; b += 256) { hist[b] = 0; cura[b] = 0; }
    __syncthreads();

    const int e0 = blockIdx.x * 4096;
    int rr[16], cc[16];
    if (e0 + 4096 <= E) {
#pragma unroll
        for (int i = 0; i < 4; ++i) {
            const int idx = e0 + i * 1024 + tid * 4;
            const int4 r4 = *reinterpret_cast<const int4*>(row + idx);
            const int4 c4 = *reinterpret_cast<const int4*>(col + idx);
            rr[i*4+0] = r4.x; rr[i*4+1] = r4.y; rr[i*4+2] = r4.z; rr[i*4+3] = r4.w;
            cc[i*4+0] = c4.x; cc[i*4+1] = c4.y; cc[i*4+2] = c4.z; cc[i*4+3] = c4.w;
        }
    } else {
#pragma unroll
        for (int i = 0; i < 4; ++i)
#pragma unroll
            for (int j = 0; j < 4; ++j) {
                const int idx = e0 + i * 1024 + tid * 4 + j;
                rr[i*4+j] = (idx < E) ? row[idx] : -1;
                cc[i*4+j] = (idx < E) ? col[idx] : 0;
            }
    }

#pragma unroll
    for (int i = 0; i < 16; ++i)
        if ((unsigned)rr[i] < (unsigned)N)
            atomicAdd(&hist[rr[i] >> BINSHIFT], 1);
    __syncthreads();

    for (int b = tid; b < NB; b += 256) {
        const int h = hist[b];
        basea[b] = h ? atomicAdd(&bin_cursor[b], h) : 0;
    }
    __syncthreads();

#pragma unroll
    for (int i = 0; i < 16; ++i) {
        const int r = rr[i];
        if ((unsigned)r < (unsigned)N) {
            const int b = r >> BINSHIFT;
            const int p = basea[b] + atomicAdd(&cura[b], 1);
            if (p < BINCAP)
                pairs[(size_t)b * BINCAP + p] =
                    (unsigned)(r & 255) | ((unsigned)cc[i] << 8);
        }
    }
}

// Phase B: one block per bin. LDS degree count -> exclusive scan -> dense
// scatter into csr[bin*BINCAP + local_off], write off/cnt per node.
__global__ __launch_bounds__(256) void build_csr(
    const int* __restrict__ bin_cursor, const unsigned* __restrict__ pairs,
    int* __restrict__ csr, int* __restrict__ offA, int* __restrict__ cntA,
    int N)
{
    __shared__ int deg[256];
    __shared__ int offs[256];
    __shared__ int cur[256];
    const int b = blockIdx.x;
    const int tid = threadIdx.x;
    deg[tid] = 0;
    __syncthreads();

    int nsize = bin_cursor[b];
    if (nsize > BINCAP) nsize = BINCAP;
    const unsigned* bp = pairs + (size_t)b * BINCAP;

    for (int i = tid; i < nsize; i += 256)
        atomicAdd(&deg[bp[i] & 255], 1);
    __syncthreads();

    const int v = deg[tid];
    offs[tid] = v;
    __syncthreads();
    for (int o = 1; o < 256; o <<= 1) {
        const int t = (tid >= o) ? offs[tid - o] : 0;
        __syncthreads();
        offs[tid] += t;
        __syncthreads();
    }
    const int excl = offs[tid] - v;
    cur[tid] = excl;
    const int node = (b << BINSHIFT) + tid;
    if (node < N) {
        offA[node] = b * BINCAP + excl;
        cntA[node] = v;
    }
    __syncthreads();

    for (int i = tid; i < nsize; i += 256) {
        const unsigned pv = bp[i];
        const int p = atomicAdd(&cur[pv & 255], 1);
        csr[(size_t)b * BINCAP + p] = (int)(pv >> 8);
    }
}

// Swizzled half-index for the x LDS tiles: logical [row][kk], row stride 128
// halves (256B). half-index ^= (row&7)<<3 spreads 256B-stride fragment reads
// across banks; 16B granules stay aligned.
__device__ __forceinline__ int swz_idx(int row, int kk) {
    return (row * FDIM + kk) ^ ((row & 7) << 3);
}

// Stage a 64x128 fp32 x tile ONCE, writing both hi and lo fp16 parts.
__device__ __forceinline__ void stage_x(
    const float* __restrict__ src, _Float16* __restrict__ dh,
    _Float16* __restrict__ dl, int n0, int nmax, int tid)
{
    const int kk0 = (tid & 15) * 8;
    const int r0  = tid >> 4;
#pragma unroll
    for (int i = 0; i < 4; ++i) {
        const int row = i * 16 + r0;
        float4 v0 = make_float4(0.f, 0.f, 0.f, 0.f), v1 = v0;
        if (n0 + row < nmax) {
            const float* p = src + (size_t)(n0 + row) * FDIM + kk0;
            v0 = *reinterpret_cast<const float4*>(p);
            v1 = *reinterpret_cast<const float4*>(p + 4);
        }
        const float vv[8] = {v0.x, v0.y, v0.z, v0.w, v1.x, v1.y, v1.z, v1.w};
        f16x8 h, l;
#pragma unroll
        for (int j = 0; j < 8; ++j) {
            _Float16 hh = (_Float16)vv[j];
            h[j] = hh;
            l[j] = (_Float16)(vv[j] - (float)hh);
        }
        const int si = swz_idx(row, kk0);
        *reinterpret_cast<f16x8*>(&dh[si]) = h;
        *reinterpret_cast<f16x8*>(&dl[si]) = l;
    }
}

// QKV projection on matrix cores, W-fragments streamed from pre-split global
// (coalesced 16B/lane, L2-resident). Block = 64-node tile, all 3 projections.
// Wave quadrant: wr0 = (wv>>1)*32, wc0 = (wv&1)*64; 2x4 frags, 24 MFMA/kc
// (afh*bfh + afl*bfh + afh*bfl). Q,V -> interleaved fp16 QVh[n][256] =
// [q0,q1,v0,v1]x64; K -> fp32 Kout (= d_out, aliased; see fused_aggregate).
__global__ __launch_bounds__(256) void qkv_gemm(
    const float* __restrict__ x, const _Float16* __restrict__ Whf,
    const _Float16* __restrict__ Wlf, __half* __restrict__ QVh,
    float* __restrict__ Kout, int N)
{
    __shared__ __align__(16) _Float16 xh[64 * 128];    // 16 KB
    __shared__ __align__(16) _Float16 xl[64 * 128];    // 16 KB

    const int n0  = blockIdx.x * 64;
    const int tid = threadIdx.x;
    const int lane = tid & 63;
    const int wv   = tid >> 6;
    const int wr0  = (wv >> 1) * 32;
    const int wc0  = (wv & 1) * 64;
    const int g0   = wc0 >> 4;          // base row-group for B frags
    const int orow = (lane >> 4) * 4;
    const int ocol = lane & 15;

    stage_x(x, xh, xl, n0, N, tid);
    __syncthreads();

    const int lrow = lane & 15;
    const int lk   = (lane >> 4) * 8;

    for (int p = 0; p < 3; ++p) {
        f32x4 acc[2][4];
#pragma unroll
        for (int a = 0; a < 2; ++a)
#pragma unroll
            for (int b = 0; b < 4; ++b)
                acc[a][b] = (f32x4){0.f, 0.f, 0.f, 0.f};

#pragma unroll
        for (int kc = 0; kc < 4; ++kc) {
            f16x8 afh[2], afl[2], bfh[4], bfl[4];
#pragma unroll
            for (int a = 0; a < 2; ++a) {
                const int si = swz_idx(wr0 + a * 16 + lrow, kc * 32 + lk);
                afh[a] = *reinterpret_cast<const f16x8*>(&xh[si]);
                afl[a] = *reinterpret_cast<const f16x8*>(&xl[si]);
            }
#pragma unroll
            for (int b = 0; b < 4; ++b) {
                const size_t off =
                    ((size_t)((p * 8 + g0 + b) * 4 + kc) * 64 + lane) * 8;
                bfh[b] = *reinterpret_cast<const f16x8*>(Whf + off);
                bfl[b] = *reinterpret_cast<const f16x8*>(Wlf + off);
            }
#pragma unroll
            for (int a = 0; a < 2; ++a)
#pragma unroll
                for (int b = 0; b < 4; ++b)
                    acc[a][b] = __builtin_amdgcn_mfma_f32_16x16x32_f16(
                        afh[a], bfh[b], acc[a][b], 0, 0, 0);
#pragma unroll
            for (int a = 0; a < 2; ++a)
#pragma unroll
                for (int b = 0; b < 4; ++b)
                    acc[a][b] = __builtin_amdgcn_mfma_f32_16x16x32_f16(
                        afl[a], bfh[b], acc[a][b], 0, 0, 0);
#pragma unroll
            for (int a = 0; a < 2; ++a)
#pragma unroll
                for (int b = 0; b < 4; ++b)
                    acc[a][b] = __builtin_amdgcn_mfma_f32_16x16x32_f16(
                        afh[a], bfl[b], acc[a][b], 0, 0, 0);
        }

        // epilogue for projection p
        if (p == 1) {
#pragma unroll
            for (int a = 0; a < 2; ++a) {
#pragma unroll
                for (int r = 0; r < 4; ++r) {
                    const int n = n0 + wr0 + a * 16 + orow + r;
                    if (n < N) {
                        float* op = Kout + (size_t)n * FDIM + wc0 + ocol;
#pragma unroll
                        for (int b = 0; b < 4; ++b)
                            op[b * 16] = acc[a][b][r];
                    }
                }
            }
        } else {
            const int voff = (p == 2) ? 2 : 0;
#pragma unroll
            for (int a = 0; a < 2; ++a) {
#pragma unroll
                for (int r = 0; r < 4; ++r) {
                    const int n = n0 + wr0 + a * 16 + orow + r;
                    if (n < N) {
                        __half* op = QVh + (size_t)n * 256;
#pragma unroll
                        for (int b = 0; b < 4; ++b) {
                            const int d_o = wc0 + ocol + b * 16;
                            op[((d_o >> 1) << 2) + (d_o & 1) + voff] =
                                __float2half(acc[a][b][r]);
                        }
                    }
                }
            }
        }
    }
}

// Fused scores+softmax+aggregate. One wave per dst node; lane holds dims
// (2*lane, 2*lane+1), head = lane>>4 (16-lane groups). K[node] fp32 from
// Kb (= out, aliased: each wave reads only its own row before writing it).
// Dense CSR: j0 = offA[node], cnt = cntA[node]; neighbor ids preloaded
// 64-wide coalesced + __shfl broadcast per chunk. Gathers: one 8B
// interleaved [q0,q1,v0,v1] load per lane per edge; 4-deep pipeline.
__global__ __launch_bounds__(256) void fused_aggregate(
    const int* __restrict__ offA, const int* __restrict__ cntA,
    const int* __restrict__ csr, const __half* __restrict__ QVh,
    const float* Kb, const float* __restrict__ D, float* out, int N)
{
    int node = blockIdx.x * 4 + (threadIdx.x >> 6);
    if (node >= N) return;
    int lane = threadIdx.x & 63;
    int d = lane * 2;
    const float2 kv = *reinterpret_cast<const float2*>(Kb + (size_t)node * FDIM + d);
    const float D0 = D[d], D1 = D[d + 1];
    const int j0  = offA[node];
    const int cnt = cntA[node];
    float a0 = 0.0f, a1 = 0.0f, se = 0.0f;

    int cc0, cc1, cc2, cc3;
    float2 t0, t1, t2, t3;

#define LOADF(s, idx) { int c_ = __shfl(ec, (idx)); cc##s = c_; \
    t##s = *reinterpret_cast<const float2*>( \
        reinterpret_cast<const __half*>(QVh) + (size_t)c_ * 256 + (lane << 2)); }

#define PROC(s) { \
    float2 qf = __half22float2(*reinterpret_cast<__half2*>(&t##s.x)); \
    float2 vf = __half22float2(*reinterpret_cast<__half2*>(&t##s.y)); \
    float p; \
    if (cc##s == node) { p = D0 * kv.x * qf.x + D1 * kv.y * qf.y; } \
    else { float dx = kv.x - qf.x, dy = kv.y - qf.y; \
           p = D0 * dx * dx + D1 * dy * dy; } \
    p += __shfl_xor(p, 1); p += __shfl_xor(p, 2); \
    p += __shfl_xor(p, 4); p += __shfl_xor(p, 8); \
    float z = p * 0.17677669529663687f; \
    z = fmaxf(z, 0.2f * z); \
    float ex = __expf(z); \
    a0 += ex * vf.x; a1 += ex * vf.y; se += ex; }

    for (int base = 0; base < cnt; base += 64) {
        const int rem = min(64, cnt - base);
        const int ec = (lane < rem) ? csr[j0 + base + lane] : 0;
        int j = 0;
        if (rem >= 4) {
            LOADF(0, 0) LOADF(1, 1) LOADF(2, 2) LOADF(3, 3)
            while (j + 8 <= rem) {
                PROC(0) LOADF(0, j + 4)
                PROC(1) LOADF(1, j + 5)
                PROC(2) LOADF(2, j + 6)
                PROC(3) LOADF(3, j + 7)
                j += 4;
            }
            PROC(0) PROC(1) PROC(2) PROC(3)
            j += 4;
        }
        for (; j < rem; ++j) {
            LOADF(0, j)
            PROC(0)
        }
    }
#undef LOADF
#undef PROC

    float inv = 1.0f / (se + 1e-16f);
    *reinterpret_cast<float2*>(out + (size_t)node * FDIM + d) =
        make_float2(a0 * inv, a1 * inv);
}

extern "C" void kernel_launch(void* const* d_in, const int* in_sizes, int n_in,
                              void* d_out, int out_size, void* d_ws, size_t ws_size,
                              hipStream_t stream) {
    const float* x  = (const float*)d_in[0];
    const float* Wq = (const float*)d_in[1];
    const float* Wk = (const float*)d_in[2];
    const float* Wv = (const float*)d_in[3];
    const float* D  = (const float*)d_in[4];
    const int*  edge = (const int*)d_in[5];
    float* out = (float*)d_out;

    const int N = in_sizes[0] / FDIM;
    const int E = in_sizes[5] / 2;
    const int* row = edge;       // edge_index[0] = destination (segment id)
    const int* col = edge + E;   // edge_index[1] = source of Q_j / V

    const int NB = (N + 255) >> 8;   // 256-node bins (<= 512)

    // Workspace: QVh[N][256] fp16 | pairs[NB*BINCAP] | csr[NB*BINCAP] |
    //            offA[N] | cntA[N] | bin_cursor[512] | Whf | Wlf
    // K buffer lives in d_out (aliased; overwritten by fused_aggregate).
    __half* QVh = (__half*)d_ws;
    unsigned* pairs = (unsigned*)(QVh + (size_t)N * 256);
    int* csr  = (int*)(pairs + (size_t)NB * BINCAP);
    int* offA = csr + (size_t)NB * BINCAP;
    int* cntA = offA + N;
    int* bin_cursor = cntA + N;
    _Float16* Whf = (_Float16*)(bin_cursor + 512);   // 3*16384 halves
    _Float16* Wlf = Whf + 3 * 16384;
    float* Kout = out;

    init_buffers<<<(NB + 255) / 256, 256, 0, stream>>>(bin_cursor, NB);
    split_w<<<3, 256, 0, stream>>>(Wq, Wk, Wv, Whf, Wlf);

    partition_edges<<<(E + 4095) / 4096, 256, 0, stream>>>(
        row, col, bin_cursor, pairs, E, N, NB);
    build_csr<<<NB, 256, 0, stream>>>(
        bin_cursor, pairs, csr, offA, cntA, N);

    qkv_gemm<<<(N + 63) / 64, 256, 0, stream>>>(
        x, Whf, Wlf, QVh, Kout, N);

    fused_aggregate<<<(N + 3) / 4, 256, 0, stream>>>(
        offA, cntA, csr, QVh, Kout, D, out, N);
}

// Round 10
// 313.196 us; speedup vs baseline: 1.3678x; 1.0041x over previous
//
#include <hip/hip_runtime.h>
#include <hip/hip_fp16.h>
#include <cmath>

// ---------------------------------------------------------------------------
// PlainGNN: Q/K/V = x@W^T ; per-edge scores = leakyrelu(scale * sum_d D*(K_i-Q_j)^2)
// (self edges: K^T diag(D) Q) ; segment-softmax over destination row ;
// out[row] += alpha * V[col].
// N=100000, E=1600000, IN_F=128, HEADS=4, D_K=32.
//
// R13: sparse bucket fill = 96MB of per-edge 64B writebacks (150us). R14:
// two-phase counting sort -> dense CSR -> 314us; fused_aggregate 123us at
// FETCH 405MB/3.78TB/s (47% HBM) AND VALUBusy 75% — co-limited; VALU time
// (~92us) ~ gather time (~107us). Gather bytes already minimal for fp16.
// R16: halve wave-instructions per edge — TWO edges per wave. QVh rows
// re-packed as 32 x 16B groups [q0..q3,v0..v3]: lane covers 4 dims via one
// 16B load; half-wave 0 = edge A, half-wave 1 = edge B. Score reduce = 3
// shfl_xor (8-lane head groups). csr stores byte offsets (col<<9). init
// folded into split_w (one fewer launch). Coalesced float4 out store.
// Odd-degree tail: both halves process the last edge with ex*0.5 (exact).
// R17: R16 bench = infra failure (same signature as R15, which was flake);
// kernel re-audited (gather ends exactly at QVh bound, shuffles in-range,
// scatter bounded) — resubmitted unchanged.
// ---------------------------------------------------------------------------

#define HEADS 4
#define DK 32
#define FDIM 128
#define BINSHIFT 8
#define BINCAP 6144          // per-bin edge capacity; mean 4096, sd 64

typedef _Float16 f16x8 __attribute__((ext_vector_type(8)));
typedef float f32x4 __attribute__((ext_vector_type(4)));

// One-time W split (+ bin_cursor zeroing, absorbing the old init kernel).
// Wq/Wk/Wv fp32 [128][128] -> fp16 hi/lo in MFMA fragment order.
// Layout: Whf/Wlf[((p*8 + g)*4 + kc)*64 + lane] * f16x8, lane l holds
// W[g*16 + (l&15)][kc*32 + (l>>4)*8 .. +7]. One block per projection.
__global__ __launch_bounds__(256) void split_w(
    const float* __restrict__ Wq, const float* __restrict__ Wk,
    const float* __restrict__ Wv, _Float16* __restrict__ Whf,
    _Float16* __restrict__ Wlf, int* __restrict__ bin_cursor, int nb)
{
    const int gid = blockIdx.x * 256 + threadIdx.x;
    if (gid < nb) bin_cursor[gid] = 0;

    const int p = blockIdx.x;
    const float* __restrict__ W = (p == 0) ? Wq : (p == 1 ? Wk : Wv);
#pragma unroll
    for (int i = 0; i < 8; ++i) {
        const int id = i * 256 + threadIdx.x;     // 0..2047
        const int g  = id >> 8;
        const int kc = (id >> 6) & 3;
        const int l  = id & 63;
        const int row  = g * 16 + (l & 15);
        const int col0 = kc * 32 + (l >> 4) * 8;
        const float* src = W + row * FDIM + col0;
        const float4 v0 = *reinterpret_cast<const float4*>(src);
        const float4 v1 = *reinterpret_cast<const float4*>(src + 4);
        const float vv[8] = {v0.x, v0.y, v0.z, v0.w, v1.x, v1.y, v1.z, v1.w};
        f16x8 h, lo;
#pragma unroll
        for (int j = 0; j < 8; ++j) {
            _Float16 hh = (_Float16)vv[j];
            h[j]  = hh;
            lo[j] = (_Float16)(vv[j] - (float)hh);
        }
        const size_t off = ((size_t)((p * 8 + g) * 4 + kc) * 64 + l) * 8;
        *reinterpret_cast<f16x8*>(Whf + off) = h;
        *reinterpret_cast<f16x8*>(Wlf + off) = lo;
    }
}

// Phase A: partition edges into 256-node bins. 4096 edges/block.
// LDS histogram -> one global atomicAdd per (block,bin) reserving a chunk ->
// scatter packed records (r&255)|(col<<8) into pairs[bin*BINCAP + pos].
__global__ __launch_bounds__(256) void partition_edges(
    const int* __restrict__ row, const int* __restrict__ col,
    int* __restrict__ bin_cursor, unsigned* __restrict__ pairs,
    int E, int N, int NB)
{
    __shared__ int hist[512];
    __shared__ int basea[512];
    __shared__ int cura[512];
    const int tid = threadIdx.x;
    for (int b = tid; b < 512; b += 256) { hist[b] = 0; cura[b] = 0; }
    __syncthreads();

    const int e0 = blockIdx.x * 4096;
    int rr[16], cc[16];
    if (e0 + 4096 <= E) {
#pragma unroll
        for (int i = 0; i < 4; ++i) {
            const int idx = e0 + i * 1024 + tid * 4;
            const int4 r4 = *reinterpret_cast<const int4*>(row + idx);
            const int4 c4 = *reinterpret_cast<const int4*>(col + idx);
            rr[i*4+0] = r4.x; rr[i*4+1] = r4.y; rr[i*4+2] = r4.z; rr[i*4+3] = r4.w;
            cc[i*4+0] = c4.x; cc[i*4+1] = c4.y; cc[i*4+2] = c4.z; cc[i*4+3] = c4.w;
        }
    } else {
#pragma unroll
        for (int i = 0; i < 4; ++i)
#pragma unroll
            for (int j = 0; j < 4; ++j) {
                const int idx = e0 + i * 1024 + tid * 4 + j;
                rr[i*4+j] = (idx < E) ? row[idx] : -1;
                cc[i*4+j] = (idx < E) ? col[idx] : 0;
            }
    }

#pragma unroll
    for (int i = 0; i < 16; ++i)
        if ((unsigned)rr[i] < (unsigned)N)
            atomicAdd(&hist[rr[i] >> BINSHIFT], 1);
    __syncthreads();

    for (int b = tid; b < NB; b += 256) {
        const int h = hist[b];
        basea[b] = h ? atomicAdd(&bin_cursor[b], h) : 0;
    }
    __syncthreads();

#pragma unroll
    for (int i = 0; i < 16; ++i) {
        const int r = rr[i];
        if ((unsigned)r < (unsigned)N) {
            const int b = r >> BINSHIFT;
            const int p = basea[b] + atomicAdd(&cura[b], 1);
            if (p < BINCAP)
                pairs[(size_t)b * BINCAP + p] =
                    (unsigned)(r & 255) | ((unsigned)cc[i] << 8);
        }
    }
}

// Phase B: one block per bin. LDS degree count -> exclusive scan -> dense
// scatter into csr[bin*BINCAP + local_off], write off/cnt per node.
// csr entries are BYTE OFFSETS into QVh (col*512) — saves shifts in fused.
__global__ __launch_bounds__(256) void build_csr(
    const int* __restrict__ bin_cursor, const unsigned* __restrict__ pairs,
    int* __restrict__ csr, int* __restrict__ offA, int* __restrict__ cntA,
    int N)
{
    __shared__ int deg[256];
    __shared__ int offs[256];
    __shared__ int cur[256];
    const int b = blockIdx.x;
    const int tid = threadIdx.x;
    deg[tid] = 0;
    __syncthreads();

    int nsize = bin_cursor[b];
    if (nsize > BINCAP) nsize = BINCAP;
    const unsigned* bp = pairs + (size_t)b * BINCAP;

    for (int i = tid; i < nsize; i += 256)
        atomicAdd(&deg[bp[i] & 255], 1);
    __syncthreads();

    const int v = deg[tid];
    offs[tid] = v;
    __syncthreads();
    for (int o = 1; o < 256; o <<= 1) {
        const int t = (tid >= o) ? offs[tid - o] : 0;
        __syncthreads();
        offs[tid] += t;
        __syncthreads();
    }
    const int excl = offs[tid] - v;
    cur[tid] = excl;
    const int node = (b << BINSHIFT) + tid;
    if (node < N) {
        offA[node] = b * BINCAP + excl;
        cntA[node] = v;
    }
    __syncthreads();

    for (int i = tid; i < nsize; i += 256) {
        const unsigned pv = bp[i];
        const int p = atomicAdd(&cur[pv & 255], 1);
        csr[(size_t)b * BINCAP + p] = (int)((pv >> 8) << 9);  // col*512 bytes
    }
}

// Swizzled half-index for the x LDS tiles: logical [row][kk], row stride 128
// halves (256B). half-index ^= (row&7)<<3 spreads 256B-stride fragment reads
// across banks; 16B granules stay aligned.
__device__ __forceinline__ int swz_idx(int row, int kk) {
    return (row * FDIM + kk) ^ ((row & 7) << 3);
}

// Stage a 64x128 fp32 x tile ONCE, writing both hi and lo fp16 parts.
__device__ __forceinline__ void stage_x(
    const float* __restrict__ src, _Float16* __restrict__ dh,
    _Float16* __restrict__ dl, int n0, int nmax, int tid)
{
    const int kk0 = (tid & 15) * 8;
    const int r0  = tid >> 4;
#pragma unroll
    for (int i = 0; i < 4; ++i) {
        const int row = i * 16 + r0;
        float4 v0 = make_float4(0.f, 0.f, 0.f, 0.f), v1 = v0;
        if (n0 + row < nmax) {
            const float* p = src + (size_t)(n0 + row) * FDIM + kk0;
            v0 = *reinterpret_cast<const float4*>(p);
            v1 = *reinterpret_cast<const float4*>(p + 4);
        }
        const float vv[8] = {v0.x, v0.y, v0.z, v0.w, v1.x, v1.y, v1.z, v1.w};
        f16x8 h, l;
#pragma unroll
        for (int j = 0; j < 8; ++j) {
            _Float16 hh = (_Float16)vv[j];
            h[j] = hh;
            l[j] = (_Float16)(vv[j] - (float)hh);
        }
        const int si = swz_idx(row, kk0);
        *reinterpret_cast<f16x8*>(&dh[si]) = h;
        *reinterpret_cast<f16x8*>(&dl[si]) = l;
    }
}

// QKV projection on matrix cores, W-fragments streamed from pre-split global
// (coalesced 16B/lane, L2-resident). Block = 64-node tile, all 3 projections.
// Wave quadrant: wr0 = (wv>>1)*32, wc0 = (wv&1)*64; 2x4 frags, 24 MFMA/kc.
// Q,V -> fp16 QVh[n] as 32 x 16B groups [q(4g..4g+3), v(4g..4g+3)];
// K -> fp32 Kout (= d_out, aliased; see fused_aggregate).
__global__ __launch_bounds__(256) void qkv_gemm(
    const float* __restrict__ x, const _Float16* __restrict__ Whf,
    const _Float16* __restrict__ Wlf, __half* __restrict__ QVh,
    float* __restrict__ Kout, int N)
{
    __shared__ __align__(16) _Float16 xh[64 * 128];    // 16 KB
    __shared__ __align__(16) _Float16 xl[64 * 128];    // 16 KB

    const int n0  = blockIdx.x * 64;
    const int tid = threadIdx.x;
    const int lane = tid & 63;
    const int wv   = tid >> 6;
    const int wr0  = (wv >> 1) * 32;
    const int wc0  = (wv & 1) * 64;
    const int g0   = wc0 >> 4;          // base row-group for B frags
    const int orow = (lane >> 4) * 4;
    const int ocol = lane & 15;

    stage_x(x, xh, xl, n0, N, tid);
    __syncthreads();

    const int lrow = lane & 15;
    const int lk   = (lane >> 4) * 8;

    for (int p = 0; p < 3; ++p) {
        f32x4 acc[2][4];
#pragma unroll
        for (int a = 0; a < 2; ++a)
#pragma unroll
            for (int b = 0; b < 4; ++b)
                acc[a][b] = (f32x4){0.f, 0.f, 0.f, 0.f};

#pragma unroll
        for (int kc = 0; kc < 4; ++kc) {
            f16x8 afh[2], afl[2], bfh[4], bfl[4];
#pragma unroll
            for (int a = 0; a < 2; ++a) {
                const int si = swz_idx(wr0 + a * 16 + lrow, kc * 32 + lk);
                afh[a] = *reinterpret_cast<const f16x8*>(&xh[si]);
                afl[a] = *reinterpret_cast<const f16x8*>(&xl[si]);
            }
#pragma unroll
            for (int b = 0; b < 4; ++b) {
                const size_t off =
                    ((size_t)((p * 8 + g0 + b) * 4 + kc) * 64 + lane) * 8;
                bfh[b] = *reinterpret_cast<const f16x8*>(Whf + off);
                bfl[b] = *reinterpret_cast<const f16x8*>(Wlf + off);
            }
#pragma unroll
            for (int a = 0; a < 2; ++a)
#pragma unroll
                for (int b = 0; b < 4; ++b)
                    acc[a][b] = __builtin_amdgcn_mfma_f32_16x16x32_f16(
                        afh[a], bfh[b], acc[a][b], 0, 0, 0);
#pragma unroll
            for (int a = 0; a < 2; ++a)
#pragma unroll
                for (int b = 0; b < 4; ++b)
                    acc[a][b] = __builtin_amdgcn_mfma_f32_16x16x32_f16(
                        afl[a], bfh[b], acc[a][b], 0, 0, 0);
#pragma unroll
            for (int a = 0; a < 2; ++a)
#pragma unroll
                for (int b = 0; b < 4; ++b)
                    acc[a][b] = __builtin_amdgcn_mfma_f32_16x16x32_f16(
                        afh[a], bfl[b], acc[a][b], 0, 0, 0);
        }

        // epilogue for projection p
        if (p == 1) {
#pragma unroll
            for (int a = 0; a < 2; ++a) {
#pragma unroll
                for (int r = 0; r < 4; ++r) {
                    const int n = n0 + wr0 + a * 16 + orow + r;
                    if (n < N) {
                        float* op = Kout + (size_t)n * FDIM + wc0 + ocol;
#pragma unroll
                        for (int b = 0; b < 4; ++b)
                            op[b * 16] = acc[a][b][r];
                    }
                }
            }
        } else {
            const int voff = (p == 2) ? 4 : 0;
#pragma unroll
            for (int a = 0; a < 2; ++a) {
#pragma unroll
                for (int r = 0; r < 4; ++r) {
                    const int n = n0 + wr0 + a * 16 + orow + r;
                    if (n < N) {
                        __half* op = QVh + (size_t)n * 256;
#pragma unroll
                        for (int b = 0; b < 4; ++b) {
                            const int d_o = wc0 + ocol + b * 16;
                            op[((d_o >> 2) << 3) + (d_o & 3) + voff] =
                                __float2half(acc[a][b][r]);
                        }
                    }
                }
            }
        }
    }
}

// Fused scores+softmax+aggregate, TWO edges per wave. One wave per dst node;
// lane = (hl, side): hl in [0,32) covers dims 4hl..4hl+3, side = edge of the
// pair. One 16B gather per lane per edge-pair. Head = 8-lane group; score
// reduce = 3 shfl_xor. K[node] fp32 from Kb (= out, aliased: wave reads only
// its own row before writing it). csr holds byte offsets (col*512).
// Odd tail: both halves process the last edge with ex*0.5 (exact).
__global__ __launch_bounds__(256) void fused_aggregate(
    const int* __restrict__ offA, const int* __restrict__ cntA,
    const int* __restrict__ csr, const __half* __restrict__ QVh,
    const float* Kb, const float* __restrict__ D, float* out, int N)
{
    int node = blockIdx.x * 4 + (threadIdx.x >> 6);
    if (node >= N) return;
    const int lane = threadIdx.x & 63;
    const int hl   = lane & 31;
    const int side = lane >> 5;
    const int d0   = hl << 2;
    const float4 kv = *reinterpret_cast<const float4*>(Kb + (size_t)node * FDIM + d0);
    const float4 Dv = *reinterpret_cast<const float4*>(D + d0);
    const float Dk0 = Dv.x * kv.x, Dk1 = Dv.y * kv.y,
                Dk2 = Dv.z * kv.z, Dk3 = Dv.w * kv.w;
    const int j0  = offA[node];
    const int cnt = cntA[node];
    const int nb  = node << 9;
    float a0 = 0.f, a1 = 0.f, a2 = 0.f, a3 = 0.f, se = 0.f;

    int cc0, cc1, cc2, cc3;
    float4 t0, t1, t2, t3;

#define LOADP(s, p) { int c_ = __shfl(ecb, 2 * (p) + side); cc##s = c_; \
    t##s = *reinterpret_cast<const float4*>( \
        reinterpret_cast<const char*>(QVh) + (size_t)(unsigned)c_ + (hl << 4)); }

#define PROCP(s) { \
    const __half2* th = reinterpret_cast<const __half2*>(&t##s); \
    float2 q01 = __half22float2(th[0]); float2 q23 = __half22float2(th[1]); \
    float2 v01 = __half22float2(th[2]); float2 v23 = __half22float2(th[3]); \
    float p; \
    if (cc##s == nb) { \
        p = Dk0 * q01.x + Dk1 * q01.y + Dk2 * q23.x + Dk3 * q23.y; \
    } else { \
        float e0 = kv.x - q01.x, e1 = kv.y - q01.y; \
        float e2 = kv.z - q23.x, e3 = kv.w - q23.y; \
        p = Dv.x*e0*e0 + Dv.y*e1*e1 + Dv.z*e2*e2 + Dv.w*e3*e3; \
    } \
    p += __shfl_xor(p, 1); p += __shfl_xor(p, 2); p += __shfl_xor(p, 4); \
    float z = p * 0.17677669529663687f; \
    z = fmaxf(z, 0.2f * z); \
    float ex = __expf(z); \
    a0 += ex * v01.x; a1 += ex * v01.y; \
    a2 += ex * v23.x; a3 += ex * v23.y; se += ex; }

    for (int base = 0; base < cnt; base += 64) {
        const int rem = min(64, cnt - base);
        const int ecb = (lane < rem) ? csr[j0 + base + lane] : 0;
        const int npair = rem >> 1;
        int pj = 0;
        if (npair >= 4) {
            LOADP(0, 0) LOADP(1, 1) LOADP(2, 2) LOADP(3, 3)
            while (pj + 8 <= npair) {
                PROCP(0) LOADP(0, pj + 4)
                PROCP(1) LOADP(1, pj + 5)
                PROCP(2) LOADP(2, pj + 6)
                PROCP(3) LOADP(3, pj + 7)
                pj += 4;
            }
            PROCP(0) PROCP(1) PROCP(2) PROCP(3)
            pj += 4;
        }
        for (; pj < npair; ++pj) {
            LOADP(0, pj)
            PROCP(0)
        }
        if (rem & 1) {
            // tail edge: both halves process it; halve ex to avoid 2x count.
            const int c_ = __shfl(ecb, rem - 1);
            float4 tt = *reinterpret_cast<const float4*>(
                reinterpret_cast<const char*>(QVh) + (size_t)(unsigned)c_ + (hl << 4));
            const __half2* th = reinterpret_cast<const __half2*>(&tt);
            float2 q01 = __half22float2(th[0]); float2 q23 = __half22float2(th[1]);
            float2 v01 = __half22float2(th[2]); float2 v23 = __half22float2(th[3]);
            float p;
            if (c_ == nb) {
                p = Dk0 * q01.x + Dk1 * q01.y + Dk2 * q23.x + Dk3 * q23.y;
            } else {
                float e0 = kv.x - q01.x, e1 = kv.y - q01.y;
                float e2 = kv.z - q23.x, e3 = kv.w - q23.y;
                p = Dv.x*e0*e0 + Dv.y*e1*e1 + Dv.z*e2*e2 + Dv.w*e3*e3;
            }
            p += __shfl_xor(p, 1); p += __shfl_xor(p, 2); p += __shfl_xor(p, 4);
            float z = p * 0.17677669529663687f;
            z = fmaxf(z, 0.2f * z);
            float ex = __expf(z) * 0.5f;
            a0 += ex * v01.x; a1 += ex * v01.y;
            a2 += ex * v23.x; a3 += ex * v23.y; se += ex;
        }
    }
#undef LOADP
#undef PROCP

    // combine the two half-waves (same dims, disjoint edge subsets)
    a0 += __shfl_xor(a0, 32); a1 += __shfl_xor(a1, 32);
    a2 += __shfl_xor(a2, 32); a3 += __shfl_xor(a3, 32);
    se += __shfl_xor(se, 32);

    if (side == 0) {
        const float inv = 1.0f / (se + 1e-16f);
        *reinterpret_cast<float4*>(out + (size_t)node * FDIM + d0) =
            make_float4(a0 * inv, a1 * inv, a2 * inv, a3 * inv);
    }
}

extern "C" void kernel_launch(void* const* d_in, const int* in_sizes, int n_in,
                              void* d_out, int out_size, void* d_ws, size_t ws_size,
                              hipStream_t stream) {
    const float* x  = (const float*)d_in[0];
    const float* Wq = (const float*)d_in[1];
    const float* Wk = (const float*)d_in[2];
    const float* Wv = (const float*)d_in[3];
    const float* D  = (const float*)d_in[4];
    const int*  edge = (const int*)d_in[5];
    float* out = (float*)d_out;

    const int N = in_sizes[0] / FDIM;
    const int E = in_sizes[5] / 2;
    const int* row = edge;       // edge_index[0] = destination (segment id)
    const int* col = edge + E;   // edge_index[1] = source of Q_j / V

    const int NB = (N + 255) >> 8;   // 256-node bins (<= 512)

    // Workspace: QVh[N][256] fp16 | pairs[NB*BINCAP] | csr[NB*BINCAP] |
    //            offA[N] | cntA[N] | bin_cursor[512] | Whf | Wlf
    // K buffer lives in d_out (aliased; overwritten by fused_aggregate).
    __half* QVh = (__half*)d_ws;
    unsigned* pairs = (unsigned*)(QVh + (size_t)N * 256);
    int* csr  = (int*)(pairs + (size_t)NB * BINCAP);
    int* offA = csr + (size_t)NB * BINCAP;
    int* cntA = offA + N;
    int* bin_cursor = cntA + N;
    _Float16* Whf = (_Float16*)(bin_cursor + 512);   // 3*16384 halves
    _Float16* Wlf = Whf + 3 * 16384;
    float* Kout = out;

    split_w<<<3, 256, 0, stream>>>(Wq, Wk, Wv, Whf, Wlf, bin_cursor, NB);

    partition_edges<<<(E + 4095) / 4096, 256, 0, stream>>>(
        row, col, bin_cursor, pairs, E, N, NB);
    build_csr<<<NB, 256, 0, stream>>>(
        bin_cursor, pairs, csr, offA, cntA, N);

    qkv_gemm<<<(N + 63) / 64, 256, 0, stream>>>(
        x, Whf, Wlf, QVh, Kout, N);

    fused_aggregate<<<(N + 3) / 4, 256, 0, stream>>>(
        offA, cntA, csr, QVh, Kout, D, out, N);
}

// Round 11
// 296.441 us; speedup vs baseline: 1.4451x; 1.0565x over previous
//
#include <hip/hip_runtime.h>
#include <hip/hip_fp16.h>
#include <cmath>

// ---------------------------------------------------------------------------
// PlainGNN: Q/K/V = x@W^T ; per-edge scores = leakyrelu(scale * sum_d D*(K_i-Q_j)^2)
// (self edges: K^T diag(D) Q) ; segment-softmax over destination row ;
// out[row] += alpha * V[col].
// N=100000, E=1600000, IN_F=128, HEADS=4, D_K=32.
//
// R14: counting-sort CSR -> 314us. R16: two-edges-per-wave fused (VALU 75->58%)
// -> 313us, fused dur UNCHANGED at 123us: FETCH 405MB @ 3.78TB/s invariant
// across 3 kernel variants => 3.8TB/s IS the random-512B-gather ceiling
// (L3-resident 51MB set); fused at ~87% of its pattern roofline. Remaining
// budget: ~190us over 4 serial launches, none >123us.
// R18: hide partition_edges under qkv — fused into ONE launch. R12's failure
// mode (uniform 64KB LDS -> 2 blocks/CU) fixed: union'd 32KB smem (qkv xh/xl
// = 32KB; partition hist/base/cur = 6KB inside it) keeps 5 blocks/CU.
// Exact proportional block interleave spreads 391 fill blocks among 1563
// qkv blocks (~1.5 per CU over the kernel) so scatter latency hides under
// MFMA. One fewer launch gap. Math identical everywhere.
// ---------------------------------------------------------------------------

#define HEADS 4
#define DK 32
#define FDIM 128
#define BINSHIFT 8
#define BINCAP 6144          // per-bin edge capacity; mean 4096, sd 64

typedef _Float16 f16x8 __attribute__((ext_vector_type(8)));
typedef float f32x4 __attribute__((ext_vector_type(4)));

// One-time W split (+ bin_cursor zeroing). Wq/Wk/Wv fp32 [128][128] -> fp16
// hi/lo in MFMA fragment order: Whf/Wlf[((p*8+g)*4+kc)*64 + lane] * f16x8,
// lane l holds W[g*16+(l&15)][kc*32+(l>>4)*8 .. +7]. One block per projection.
__global__ __launch_bounds__(256) void split_w(
    const float* __restrict__ Wq, const float* __restrict__ Wk,
    const float* __restrict__ Wv, _Float16* __restrict__ Whf,
    _Float16* __restrict__ Wlf, int* __restrict__ bin_cursor, int nb)
{
    const int gid = blockIdx.x * 256 + threadIdx.x;
    if (gid < nb) bin_cursor[gid] = 0;

    const int p = blockIdx.x;
    const float* __restrict__ W = (p == 0) ? Wq : (p == 1 ? Wk : Wv);
#pragma unroll
    for (int i = 0; i < 8; ++i) {
        const int id = i * 256 + threadIdx.x;     // 0..2047
        const int g  = id >> 8;
        const int kc = (id >> 6) & 3;
        const int l  = id & 63;
        const int row  = g * 16 + (l & 15);
        const int col0 = kc * 32 + (l >> 4) * 8;
        const float* src = W + row * FDIM + col0;
        const float4 v0 = *reinterpret_cast<const float4*>(src);
        const float4 v1 = *reinterpret_cast<const float4*>(src + 4);
        const float vv[8] = {v0.x, v0.y, v0.z, v0.w, v1.x, v1.y, v1.z, v1.w};
        f16x8 h, lo;
#pragma unroll
        for (int j = 0; j < 8; ++j) {
            _Float16 hh = (_Float16)vv[j];
            h[j]  = hh;
            lo[j] = (_Float16)(vv[j] - (float)hh);
        }
        const size_t off = ((size_t)((p * 8 + g) * 4 + kc) * 64 + l) * 8;
        *reinterpret_cast<f16x8*>(Whf + off) = h;
        *reinterpret_cast<f16x8*>(Wlf + off) = lo;
    }
}

// Swizzled half-index for the x LDS tiles: logical [row][kk], row stride 128
// halves (256B). half-index ^= (row&7)<<3 spreads 256B-stride fragment reads
// across banks; 16B granules stay aligned.
__device__ __forceinline__ int swz_idx(int row, int kk) {
    return (row * FDIM + kk) ^ ((row & 7) << 3);
}

// Stage a 64x128 fp32 x tile ONCE, writing both hi and lo fp16 parts.
__device__ __forceinline__ void stage_x(
    const float* __restrict__ src, _Float16* __restrict__ dh,
    _Float16* __restrict__ dl, int n0, int nmax, int tid)
{
    const int kk0 = (tid & 15) * 8;
    const int r0  = tid >> 4;
#pragma unroll
    for (int i = 0; i < 4; ++i) {
        const int row = i * 16 + r0;
        float4 v0 = make_float4(0.f, 0.f, 0.f, 0.f), v1 = v0;
        if (n0 + row < nmax) {
            const float* p = src + (size_t)(n0 + row) * FDIM + kk0;
            v0 = *reinterpret_cast<const float4*>(p);
            v1 = *reinterpret_cast<const float4*>(p + 4);
        }
        const float vv[8] = {v0.x, v0.y, v0.z, v0.w, v1.x, v1.y, v1.z, v1.w};
        f16x8 h, l;
#pragma unroll
        for (int j = 0; j < 8; ++j) {
            _Float16 hh = (_Float16)vv[j];
            h[j] = hh;
            l[j] = (_Float16)(vv[j] - (float)hh);
        }
        const int si = swz_idx(row, kk0);
        *reinterpret_cast<f16x8*>(&dh[si]) = h;
        *reinterpret_cast<f16x8*>(&dl[si]) = l;
    }
}

// Combined kernel: qkv projection blocks + edge-partition blocks in ONE
// launch, proportionally interleaved. Union'd 32KB smem: qkv uses all of it
// (xh 16KB + xl 16KB); partition uses 6KB of it (hist/base/cur). 5 blocks/CU.
// qkv: matrix cores, fp16 Markidis split, W-frags streamed from pre-split
// global (L2-resident). Q,V -> fp16 QVh[n] as 32 x 16B groups [q0..3,v0..3];
// K -> fp32 Kout (= d_out, aliased; see fused_aggregate).
// partition: 4096 edges/block, LDS histogram -> one global atomic per
// (block,bin) -> packed records (r&255)|(col<<8) into bin regions.
__global__ __launch_bounds__(256) void qkv_and_partition(
    const float* __restrict__ x, const _Float16* __restrict__ Whf,
    const _Float16* __restrict__ Wlf, __half* __restrict__ QVh,
    float* __restrict__ Kout, int N, int NQ, int NF,
    const int* __restrict__ row, const int* __restrict__ col,
    int* __restrict__ bin_cursor, unsigned* __restrict__ pairs, int E, int NB)
{
    __shared__ __align__(16) char smem[32768];

    // proportional interleave: exactly NF f-blocks spread over NQ+NF bids.
    const long T = (long)NQ + NF;
    const long bid = blockIdx.x;
    const int fprev = (int)((bid * NF) / T);
    const int fcur  = (int)(((bid + 1) * NF) / T);

    if (fcur > fprev) {
        // ---- partition block fidx = fprev ----
        int* hist  = (int*)smem;          // 512
        int* basea = hist + 512;          // 512
        int* cura  = basea + 512;         // 512  (6KB total)
        const int tid = threadIdx.x;
        for (int b = tid; b < 512; b += 256) { hist[b] = 0; cura[b] = 0; }
        __syncthreads();

        const int e0 = fprev * 4096;
        int rr[16], cc[16];
        if (e0 + 4096 <= E) {
#pragma unroll
            for (int i = 0; i < 4; ++i) {
                const int idx = e0 + i * 1024 + tid * 4;
                const int4 r4 = *reinterpret_cast<const int4*>(row + idx);
                const int4 c4 = *reinterpret_cast<const int4*>(col + idx);
                rr[i*4+0] = r4.x; rr[i*4+1] = r4.y; rr[i*4+2] = r4.z; rr[i*4+3] = r4.w;
                cc[i*4+0] = c4.x; cc[i*4+1] = c4.y; cc[i*4+2] = c4.z; cc[i*4+3] = c4.w;
            }
        } else {
#pragma unroll
            for (int i = 0; i < 4; ++i)
#pragma unroll
                for (int j = 0; j < 4; ++j) {
                    const int idx = e0 + i * 1024 + tid * 4 + j;
                    rr[i*4+j] = (idx < E) ? row[idx] : -1;
                    cc[i*4+j] = (idx < E) ? col[idx] : 0;
                }
        }

#pragma unroll
        for (int i = 0; i < 16; ++i)
            if ((unsigned)rr[i] < (unsigned)N)
                atomicAdd(&hist[rr[i] >> BINSHIFT], 1);
        __syncthreads();

        for (int b = tid; b < NB; b += 256) {
            const int h = hist[b];
            basea[b] = h ? atomicAdd(&bin_cursor[b], h) : 0;
        }
        __syncthreads();

#pragma unroll
        for (int i = 0; i < 16; ++i) {
            const int r = rr[i];
            if ((unsigned)r < (unsigned)N) {
                const int b = r >> BINSHIFT;
                const int p = basea[b] + atomicAdd(&cura[b], 1);
                if (p < BINCAP)
                    pairs[(size_t)b * BINCAP + p] =
                        (unsigned)(r & 255) | ((unsigned)cc[i] << 8);
            }
        }
        return;
    }

    // ---- qkv block qidx = bid - fprev ----
    _Float16* xh = (_Float16*)smem;            // 16 KB
    _Float16* xl = (_Float16*)(smem + 16384);  // 16 KB

    const int qidx = (int)bid - fprev;
    const int n0  = qidx * 64;
    const int tid = threadIdx.x;
    const int lane = tid & 63;
    const int wv   = tid >> 6;
    const int wr0  = (wv >> 1) * 32;
    const int wc0  = (wv & 1) * 64;
    const int g0   = wc0 >> 4;          // base row-group for B frags
    const int orow = (lane >> 4) * 4;
    const int ocol = lane & 15;

    stage_x(x, xh, xl, n0, N, tid);
    __syncthreads();

    const int lrow = lane & 15;
    const int lk   = (lane >> 4) * 8;

    for (int p = 0; p < 3; ++p) {
        f32x4 acc[2][4];
#pragma unroll
        for (int a = 0; a < 2; ++a)
#pragma unroll
            for (int b = 0; b < 4; ++b)
                acc[a][b] = (f32x4){0.f, 0.f, 0.f, 0.f};

#pragma unroll
        for (int kc = 0; kc < 4; ++kc) {
            f16x8 afh[2], afl[2], bfh[4], bfl[4];
#pragma unroll
            for (int a = 0; a < 2; ++a) {
                const int si = swz_idx(wr0 + a * 16 + lrow, kc * 32 + lk);
                afh[a] = *reinterpret_cast<const f16x8*>(&xh[si]);
                afl[a] = *reinterpret_cast<const f16x8*>(&xl[si]);
            }
#pragma unroll
            for (int b = 0; b < 4; ++b) {
                const size_t off =
                    ((size_t)((p * 8 + g0 + b) * 4 + kc) * 64 + lane) * 8;
                bfh[b] = *reinterpret_cast<const f16x8*>(Whf + off);
                bfl[b] = *reinterpret_cast<const f16x8*>(Wlf + off);
            }
#pragma unroll
            for (int a = 0; a < 2; ++a)
#pragma unroll
                for (int b = 0; b < 4; ++b)
                    acc[a][b] = __builtin_amdgcn_mfma_f32_16x16x32_f16(
                        afh[a], bfh[b], acc[a][b], 0, 0, 0);
#pragma unroll
            for (int a = 0; a < 2; ++a)
#pragma unroll
                for (int b = 0; b < 4; ++b)
                    acc[a][b] = __builtin_amdgcn_mfma_f32_16x16x32_f16(
                        afl[a], bfh[b], acc[a][b], 0, 0, 0);
#pragma unroll
            for (int a = 0; a < 2; ++a)
#pragma unroll
                for (int b = 0; b < 4; ++b)
                    acc[a][b] = __builtin_amdgcn_mfma_f32_16x16x32_f16(
                        afh[a], bfl[b], acc[a][b], 0, 0, 0);
        }

        // epilogue for projection p
        if (p == 1) {
#pragma unroll
            for (int a = 0; a < 2; ++a) {
#pragma unroll
                for (int r = 0; r < 4; ++r) {
                    const int n = n0 + wr0 + a * 16 + orow + r;
                    if (n < N) {
                        float* op = Kout + (size_t)n * FDIM + wc0 + ocol;
#pragma unroll
                        for (int b = 0; b < 4; ++b)
                            op[b * 16] = acc[a][b][r];
                    }
                }
            }
        } else {
            const int voff = (p == 2) ? 4 : 0;
#pragma unroll
            for (int a = 0; a < 2; ++a) {
#pragma unroll
                for (int r = 0; r < 4; ++r) {
                    const int n = n0 + wr0 + a * 16 + orow + r;
                    if (n < N) {
                        __half* op = QVh + (size_t)n * 256;
#pragma unroll
                        for (int b = 0; b < 4; ++b) {
                            const int d_o = wc0 + ocol + b * 16;
                            op[((d_o >> 2) << 3) + (d_o & 3) + voff] =
                                __float2half(acc[a][b][r]);
                        }
                    }
                }
            }
        }
    }
}

// Phase B: one block per bin. LDS degree count -> exclusive scan -> dense
// scatter into csr[bin*BINCAP + local_off], write off/cnt per node.
// csr entries are BYTE OFFSETS into QVh (col*512) — saves shifts in fused.
__global__ __launch_bounds__(256) void build_csr(
    const int* __restrict__ bin_cursor, const unsigned* __restrict__ pairs,
    int* __restrict__ csr, int* __restrict__ offA, int* __restrict__ cntA,
    int N)
{
    __shared__ int deg[256];
    __shared__ int offs[256];
    __shared__ int cur[256];
    const int b = blockIdx.x;
    const int tid = threadIdx.x;
    deg[tid] = 0;
    __syncthreads();

    int nsize = bin_cursor[b];
    if (nsize > BINCAP) nsize = BINCAP;
    const unsigned* bp = pairs + (size_t)b * BINCAP;

    for (int i = tid; i < nsize; i += 256)
        atomicAdd(&deg[bp[i] & 255], 1);
    __syncthreads();

    const int v = deg[tid];
    offs[tid] = v;
    __syncthreads();
    for (int o = 1; o < 256; o <<= 1) {
        const int t = (tid >= o) ? offs[tid - o] : 0;
        __syncthreads();
        offs[tid] += t;
        __syncthreads();
    }
    const int excl = offs[tid] - v;
    cur[tid] = excl;
    const int node = (b << BINSHIFT) + tid;
    if (node < N) {
        offA[node] = b * BINCAP + excl;
        cntA[node] = v;
    }
    __syncthreads();

    for (int i = tid; i < nsize; i += 256) {
        const unsigned pv = bp[i];
        const int p = atomicAdd(&cur[pv & 255], 1);
        csr[(size_t)b * BINCAP + p] = (int)((pv >> 8) << 9);  // col*512 bytes
    }
}

// Fused scores+softmax+aggregate, TWO edges per wave. One wave per dst node;
// lane = (hl, side): hl in [0,32) covers dims 4hl..4hl+3, side = edge of the
// pair. One 16B gather per lane per edge-pair. Head = 8-lane group; score
// reduce = 3 shfl_xor. K[node] fp32 from Kb (= out, aliased: wave reads only
// its own row before writing it). csr holds byte offsets (col*512).
// Odd tail: both halves process the last edge with ex*0.5 (exact).
__global__ __launch_bounds__(256) void fused_aggregate(
    const int* __restrict__ offA, const int* __restrict__ cntA,
    const int* __restrict__ csr, const __half* __restrict__ QVh,
    const float* Kb, const float* __restrict__ D, float* out, int N)
{
    int node = blockIdx.x * 4 + (threadIdx.x >> 6);
    if (node >= N) return;
    const int lane = threadIdx.x & 63;
    const int hl   = lane & 31;
    const int side = lane >> 5;
    const int d0   = hl << 2;
    const float4 kv = *reinterpret_cast<const float4*>(Kb + (size_t)node * FDIM + d0);
    const float4 Dv = *reinterpret_cast<const float4*>(D + d0);
    const float Dk0 = Dv.x * kv.x, Dk1 = Dv.y * kv.y,
                Dk2 = Dv.z * kv.z, Dk3 = Dv.w * kv.w;
    const int j0  = offA[node];
    const int cnt = cntA[node];
    const int nb  = node << 9;
    float a0 = 0.f, a1 = 0.f, a2 = 0.f, a3 = 0.f, se = 0.f;

    int cc0, cc1, cc2, cc3;
    float4 t0, t1, t2, t3;

#define LOADP(s, p) { int c_ = __shfl(ecb, 2 * (p) + side); cc##s = c_; \
    t##s = *reinterpret_cast<const float4*>( \
        reinterpret_cast<const char*>(QVh) + (size_t)(unsigned)c_ + (hl << 4)); }

#define PROCP(s) { \
    const __half2* th = reinterpret_cast<const __half2*>(&t##s); \
    float2 q01 = __half22float2(th[0]); float2 q23 = __half22float2(th[1]); \
    float2 v01 = __half22float2(th[2]); float2 v23 = __half22float2(th[3]); \
    float p; \
    if (cc##s == nb) { \
        p = Dk0 * q01.x + Dk1 * q01.y + Dk2 * q23.x + Dk3 * q23.y; \
    } else { \
        float e0 = kv.x - q01.x, e1 = kv.y - q01.y; \
        float e2 = kv.z - q23.x, e3 = kv.w - q23.y; \
        p = Dv.x*e0*e0 + Dv.y*e1*e1 + Dv.z*e2*e2 + Dv.w*e3*e3; \
    } \
    p += __shfl_xor(p, 1); p += __shfl_xor(p, 2); p += __shfl_xor(p, 4); \
    float z = p * 0.17677669529663687f; \
    z = fmaxf(z, 0.2f * z); \
    float ex = __expf(z); \
    a0 += ex * v01.x; a1 += ex * v01.y; \
    a2 += ex * v23.x; a3 += ex * v23.y; se += ex; }

    for (int base = 0; base < cnt; base += 64) {
        const int rem = min(64, cnt - base);
        const int ecb = (lane < rem) ? csr[j0 + base + lane] : 0;
        const int npair = rem >> 1;
        int pj = 0;
        if (npair >= 4) {
            LOADP(0, 0) LOADP(1, 1) LOADP(2, 2) LOADP(3, 3)
            while (pj + 8 <= npair) {
                PROCP(0) LOADP(0, pj + 4)
                PROCP(1) LOADP(1, pj + 5)
                PROCP(2) LOADP(2, pj + 6)
                PROCP(3) LOADP(3, pj + 7)
                pj += 4;
            }
            PROCP(0) PROCP(1) PROCP(2) PROCP(3)
            pj += 4;
        }
        for (; pj < npair; ++pj) {
            LOADP(0, pj)
            PROCP(0)
        }
        if (rem & 1) {
            // tail edge: both halves process it; halve ex to avoid 2x count.
            const int c_ = __shfl(ecb, rem - 1);
            float4 tt = *reinterpret_cast<const float4*>(
                reinterpret_cast<const char*>(QVh) + (size_t)(unsigned)c_ + (hl << 4));
            const __half2* th = reinterpret_cast<const __half2*>(&tt);
            float2 q01 = __half22float2(th[0]); float2 q23 = __half22float2(th[1]);
            float2 v01 = __half22float2(th[2]); float2 v23 = __half22float2(th[3]);
            float p;
            if (c_ == nb) {
                p = Dk0 * q01.x + Dk1 * q01.y + Dk2 * q23.x + Dk3 * q23.y;
            } else {
                float e0 = kv.x - q01.x, e1 = kv.y - q01.y;
                float e2 = kv.z - q23.x, e3 = kv.w - q23.y;
                p = Dv.x*e0*e0 + Dv.y*e1*e1 + Dv.z*e2*e2 + Dv.w*e3*e3;
            }
            p += __shfl_xor(p, 1); p += __shfl_xor(p, 2); p += __shfl_xor(p, 4);
            float z = p * 0.17677669529663687f;
            z = fmaxf(z, 0.2f * z);
            float ex = __expf(z) * 0.5f;
            a0 += ex * v01.x; a1 += ex * v01.y;
            a2 += ex * v23.x; a3 += ex * v23.y; se += ex;
        }
    }
#undef LOADP
#undef PROCP

    // combine the two half-waves (same dims, disjoint edge subsets)
    a0 += __shfl_xor(a0, 32); a1 += __shfl_xor(a1, 32);
    a2 += __shfl_xor(a2, 32); a3 += __shfl_xor(a3, 32);
    se += __shfl_xor(se, 32);

    if (side == 0) {
        const float inv = 1.0f / (se + 1e-16f);
        *reinterpret_cast<float4*>(out + (size_t)node * FDIM + d0) =
            make_float4(a0 * inv, a1 * inv, a2 * inv, a3 * inv);
    }
}

extern "C" void kernel_launch(void* const* d_in, const int* in_sizes, int n_in,
                              void* d_out, int out_size, void* d_ws, size_t ws_size,
                              hipStream_t stream) {
    const float* x  = (const float*)d_in[0];
    const float* Wq = (const float*)d_in[1];
    const float* Wk = (const float*)d_in[2];
    const float* Wv = (const float*)d_in[3];
    const float* D  = (const float*)d_in[4];
    const int*  edge = (const int*)d_in[5];
    float* out = (float*)d_out;

    const int N = in_sizes[0] / FDIM;
    const int E = in_sizes[5] / 2;
    const int* row = edge;       // edge_index[0] = destination (segment id)
    const int* col = edge + E;   // edge_index[1] = source of Q_j / V

    const int NB = (N + 255) >> 8;   // 256-node bins (<= 512)

    // Workspace: QVh[N][256] fp16 | pairs[NB*BINCAP] | csr[NB*BINCAP] |
    //            offA[N] | cntA[N] | bin_cursor[512] | Whf | Wlf
    // K buffer lives in d_out (aliased; overwritten by fused_aggregate).
    __half* QVh = (__half*)d_ws;
    unsigned* pairs = (unsigned*)(QVh + (size_t)N * 256);
    int* csr  = (int*)(pairs + (size_t)NB * BINCAP);
    int* offA = csr + (size_t)NB * BINCAP;
    int* cntA = offA + N;
    int* bin_cursor = cntA + N;
    _Float16* Whf = (_Float16*)(bin_cursor + 512);   // 3*16384 halves
    _Float16* Wlf = Whf + 3 * 16384;
    float* Kout = out;

    const int NQ = (N + 63) / 64;
    const int NF = (E + 4095) / 4096;

    split_w<<<3, 256, 0, stream>>>(Wq, Wk, Wv, Whf, Wlf, bin_cursor, NB);

    qkv_and_partition<<<NQ + NF, 256, 0, stream>>>(
        x, Whf, Wlf, QVh, Kout, N, NQ, NF, row, col, bin_cursor, pairs, E, NB);

    build_csr<<<NB, 256, 0, stream>>>(
        bin_cursor, pairs, csr, offA, cntA, N);

    fused_aggregate<<<(N + 3) / 4, 256, 0, stream>>>(
        offA, cntA, csr, QVh, Kout, D, out, N);
}